// Round 20
// baseline (1904.880 us; speedup 1.0000x reference)
//
#include <hip/hip_runtime.h>
#include <stdint.h>

// Problem constants (ComplexChebTemporalConv)
#define Bn 4
#define Nn 2048
#define Tn 64
#define CIn 32
#define COn 32
#define Kn 6
#define TAUn 3
#define Jn 8192  // B*T*CI

typedef _Float16 f16;
typedef _Float16 f16x2 __attribute__((ext_vector_type(2)));
typedef _Float16 f16x4 __attribute__((ext_vector_type(4)));
typedef _Float16 f16x8 __attribute__((ext_vector_type(8)));
typedef float f32x4 __attribute__((ext_vector_type(4)));

template <int N> struct ic { static constexpr int v = N; };

#if defined(__has_builtin)
#if __has_builtin(__builtin_amdgcn_fdot2)
#define HAVE_FDOT2 1
#endif
#endif

__device__ __forceinline__ float fdot2(f16x2 a, f16x2 b, float c) {
#ifdef HAVE_FDOT2
  return __builtin_amdgcn_fdot2(a, b, c, false);
#else
  return c + (float)a[0] * (float)b[0] + (float)a[1] * (float)b[1];
#endif
}

__device__ __forceinline__ void gld_lds16(const void* g, void* l) {
  auto gp = (const __attribute__((address_space(1))) uint32_t*)(uintptr_t)g;
  auto lp = (__attribute__((address_space(3))) uint32_t*)(uint32_t)(uintptr_t)l;
  __builtin_amdgcn_global_load_lds(gp, lp, 16, 0, 0);
}

// ---------------------------------------------------------------------------
// pack_gso: fp32 gso planes -> f16 planes (row-major [n][m])
// ---------------------------------------------------------------------------
__global__ __launch_bounds__(256) void pack_gso(const float* __restrict__ gr,
                                                const float* __restrict__ gi,
                                                f16* __restrict__ Gr,
                                                f16* __restrict__ Gi) {
  int u = blockIdx.x * 256 + threadIdx.x;
  float4 vr = ((const float4*)gr)[u];
  float4 vi = ((const float4*)gi)[u];
  f16x4 hr, hi;
  hr[0] = (f16)vr.x; hr[1] = (f16)vr.y; hr[2] = (f16)vr.z; hr[3] = (f16)vr.w;
  hi[0] = (f16)vi.x; hi[1] = (f16)vi.y; hi[2] = (f16)vi.z; hi[3] = (f16)vi.w;
  ((f16x4*)Gr)[u] = hr;
  ((f16x4*)Gi)[u] = hi;
}

// ---------------------------------------------------------------------------
// pack_x: x [b][n][q] fp32 -> combined P0[j=b*2048+q][4096]: re at col n, im at 2048+n
// ---------------------------------------------------------------------------
__global__ __launch_bounds__(256) void pack_x(const float* __restrict__ xr,
                                              const float* __restrict__ xi,
                                              f16* __restrict__ P0) {
  __shared__ float tile[64][65];
  const int t = threadIdx.x;
  const int q0 = blockIdx.x * 64;
  const int n0 = blockIdx.y * 64;
  const int b = blockIdx.z;
  const int rr = t >> 4;
  const int cc = (t & 15) * 4;
  #pragma unroll
  for (int plane = 0; plane < 2; ++plane) {
    const float* src = plane ? xi : xr;
    if (plane) __syncthreads();
    #pragma unroll
    for (int it = 0; it < 4; ++it) {
      int n = it * 16 + rr;
      float4 v = *(const float4*)(src + ((size_t)b * Nn + n0 + n) * 2048 + q0 + cc);
      tile[n][cc + 0] = v.x; tile[n][cc + 1] = v.y;
      tile[n][cc + 2] = v.z; tile[n][cc + 3] = v.w;
    }
    __syncthreads();
    #pragma unroll
    for (int it = 0; it < 4; ++it) {
      int q = it * 16 + rr;
      f16x4 hv;
      hv[0] = (f16)tile[cc + 0][q];
      hv[1] = (f16)tile[cc + 1][q];
      hv[2] = (f16)tile[cc + 2][q];
      hv[3] = (f16)tile[cc + 3][q];
      *(f16x4*)(P0 + ((size_t)b * 2048 + q0 + q) * 4096 + plane * 2048 + n0 + cc) = hv;
    }
  }
}

// ---------------------------------------------------------------------------
// pack_w: wpk[idx].x = (wr, -wi), wpk[idx].y = (wi, wr); idx = [k][tau][ci][co]
// ---------------------------------------------------------------------------
__global__ __launch_bounds__(256) void pack_w(const float* __restrict__ wr,
                                              const float* __restrict__ wi,
                                              uint2* __restrict__ wpk) {
  int idx = blockIdx.x * 256 + threadIdx.x;
  if (idx >= Kn * TAUn * CIn * COn) return;
  float r = wr[idx], i = wi[idx];
  uint16_t hr = __builtin_bit_cast(uint16_t, (f16)r);
  uint16_t hi = __builtin_bit_cast(uint16_t, (f16)i);
  uint16_t hni = __builtin_bit_cast(uint16_t, (f16)(-i));
  uint2 o;
  o.x = (uint32_t)hr | ((uint32_t)hni << 16);
  o.y = (uint32_t)hi | ((uint32_t)hr << 16);
  wpk[idx] = o;
}

// ---------------------------------------------------------------------------
// cheb_gemm3 r20 = r19 KARATSUBA kernel with 3 blocks/CU.
// r19 post-mortem: per-tile wall time pinned ~2400cyc at 2 blocks/CU
// (r12 32-MFMA tile == r19 24-MFMA tile) -> latency/sync floor, not work.
// LDS 48KB -> 3 blocks fit (144 <= 160KB); VGPR 88 <= 168 (3 waves/SIMD).
// launch_bounds(256,3) is the ONLY change vs r19.
//   m1 = Gr.Pr, m2 = Gi.Pi, m3 = (Gr+Gi).(Pr+Pi);
//   Cr = m1 - m2, Ci = m3 - m1 - m2 (sums in-register, -25% FLOPs).
// 256 thr = 4 waves (2M x 2N); tile 128(n) x 64(j), BK=32, wave 64x32.
// Per tile: gate vmcnt(6)+bar; 12 frag ds_reads; lgkmcnt(0)+bar; stage kt+2
// (6 ops, parity E); MFMA m1(8), m2(8), reg-sums, m3(8) with setprio.
// Prologue: tiles 0,1 in order [Ar,Ai,Br,Bi] = 12 ops (steady-state queue).
// Epilogue: Cr -> Q[j][n], Ci -> Q[j][2048+n] (combined plane unchanged).
// MODE 0: Q = C ; MODE 1: Q = 2C - Q (in place).
// XCD swizzle: xcd owns bj 16 x bn 16; window 8x8 per quadrant (A panels
// shared between vertically adjacent quadrants -> 3-block window ~16MB/XCD).
// ---------------------------------------------------------------------------
template <int MODE>
__global__ __launch_bounds__(256, 3) void cheb_gemm3(
    const f16* __restrict__ Gr, const f16* __restrict__ Gi,
    const f16* __restrict__ P, f16* __restrict__ Q) {
  extern __shared__ __align__(16) char lds[];
  f16* L = (f16*)lds;

  const int tid = threadIdx.x;
  const int lane = tid & 63;
  const int w = tid >> 6;
  const int wm = w >> 1;              // 0..1 : 64-row n-strip
  const int wn = w & 1;               // 0..1 : 32-row j-strip
  const int sub = lane >> 4, rr = lane & 15;

  const int bid = blockIdx.x;
  const int xcd = bid & 7;
  const int l = bid >> 3;             // 0..255 in-XCD
  const int s = l & 63, w2 = l >> 6;  // window pos / quadrant
  const int bj = xcd * 16 + (w2 & 1) * 8 + (s >> 3);  // 0..127
  const int bn = (w2 >> 1) * 8 + (s & 7);             // 0..15
  const int n0 = bn * 128, j0 = bj * 64;

  // ---- staging invariants (coalesced, global-side swizzle; r14 algebra) ----
  const int srow = tid >> 2;                        // 0..63
  const int kcg = (tid & 3) ^ ((tid >> 3) & 3);     // swizzled 16B k-chunk
  const size_t aoffg = (size_t)(n0 + srow) * 2048 + kcg * 8;
  const size_t boffg = (size_t)(j0 + srow) * 4096 + kcg * 8;
  const int sdst = w * 512;                         // wave-uniform LDS base

  // ---- frag-read invariants (un-swizzle) ----
  const int arb = rr * 32 + (sub ^ ((rr >> 1) & 3)) * 8;

  // slot bases (f16 elems), parity E: base = E*12288
  //   Ar +0 (4096), Ai +4096 (4096), Br +8192 (2048), Bi +10240 (2048)
  auto stageA = [&](const f16* plane, int kcol, int slot) {  // 128r x 32k, 2 ops
    #pragma unroll
    for (int p = 0; p < 2; ++p)
      gld_lds16(plane + aoffg + p * 131072 + kcol,
                L + slot + p * 2048 + sdst);
  };
  auto stageB = [&](int pl, int kcol, int slot) {            // 64r x 32k, 1 op
    gld_lds16(P + boffg + pl * 2048 + kcol, L + slot + sdst);
  };

  f32x4 ac1[4][2] = {}, ac2[4][2] = {}, ac3[4][2] = {};
  f16x8 ar[4], ai[4], br[2], bi[2];

  // prologue: tiles 0,1 in steady-state queue order (12 ops)
  stageA(Gr, 0, 0);
  stageA(Gi, 0, 4096);
  stageB(0, 0, 8192);
  stageB(1, 0, 10240);
  stageA(Gr, 32, 12288);
  stageA(Gi, 32, 16384);
  stageB(0, 32, 20480);
  stageB(1, 32, 22528);

  for (int k2 = 0; k2 < 32; ++k2) {
    const int ktb = k2 * 2;

    auto tile = [&](auto ec) {
      constexpr int E = decltype(ec)::v;
      constexpr int AB = E * 12288;
      const int kt = ktb + E;
      const int kcol2 = ((kt + 2) & 63) * 32;  // wrap -> dummy restage

      // gate: tile kt's 6 ops retired; tile kt+1's 6 stay in flight
      asm volatile("s_waitcnt vmcnt(6)" ::: "memory");
      __builtin_amdgcn_s_barrier();

      // frag reads (12 x ds_read_b128)
      #pragma unroll
      for (int f = 0; f < 4; ++f) {
        int ro = wm * 2048 + f * 512 + arb;
        ar[f] = *(const f16x8*)(L + AB + ro);
        ai[f] = *(const f16x8*)(L + AB + 4096 + ro);
      }
      #pragma unroll
      for (int fc = 0; fc < 2; ++fc) {
        int ro = wn * 1024 + fc * 512 + arb;
        br[fc] = *(const f16x8*)(L + AB + 8192 + ro);
        bi[fc] = *(const f16x8*)(L + AB + 10240 + ro);
      }

      // mid: drain frag reads -> parity-E slots free for depth-2 stages
      asm volatile("s_waitcnt lgkmcnt(0)" ::: "memory");
      __builtin_amdgcn_s_barrier();
      stageA(Gr, kcol2, AB);
      stageA(Gi, kcol2, AB + 4096);
      stageB(0, kcol2, AB + 8192);
      stageB(1, kcol2, AB + 10240);

      __builtin_amdgcn_s_setprio(1);
      #pragma unroll
      for (int f = 0; f < 4; ++f)
        #pragma unroll
        for (int fc = 0; fc < 2; ++fc)
          ac1[f][fc] = __builtin_amdgcn_mfma_f32_16x16x32_f16(
              ar[f], br[fc], ac1[f][fc], 0, 0, 0);
      #pragma unroll
      for (int f = 0; f < 4; ++f)
        #pragma unroll
        for (int fc = 0; fc < 2; ++fc)
          ac2[f][fc] = __builtin_amdgcn_mfma_f32_16x16x32_f16(
              ai[f], bi[fc], ac2[f][fc], 0, 0, 0);
      __builtin_amdgcn_s_setprio(0);
      // register sums (Gs/Ps never materialized)
      #pragma unroll
      for (int f = 0; f < 4; ++f) ar[f] = ar[f] + ai[f];
      #pragma unroll
      for (int fc = 0; fc < 2; ++fc) br[fc] = br[fc] + bi[fc];
      __builtin_amdgcn_s_setprio(1);
      #pragma unroll
      for (int f = 0; f < 4; ++f)
        #pragma unroll
        for (int fc = 0; fc < 2; ++fc)
          ac3[f][fc] = __builtin_amdgcn_mfma_f32_16x16x32_f16(
              ar[f], br[fc], ac3[f][fc], 0, 0, 0);
      __builtin_amdgcn_s_setprio(0);
    };

    tile(ic<0>{});
    tile(ic<1>{});
  }

  asm volatile("s_waitcnt vmcnt(0)" ::: "memory");

  // Epilogue: Cr = m1-m2 -> Q[j][n]; Ci = m3-m1-m2 -> Q[j][2048+n].
  // C/D map: col=lane&15 (j), row=(lane>>4)*4+r (n).
  #pragma unroll
  for (int fc = 0; fc < 2; ++fc) {
    size_t j = (size_t)j0 + wn * 32 + fc * 16 + (lane & 15);
    #pragma unroll
    for (int fr = 0; fr < 4; ++fr) {
      int nn = n0 + wm * 64 + fr * 16 + ((lane >> 4) << 2);
      size_t offr = j * 4096 + nn;
      f16x4 vr, vi;
      if (MODE == 1) {
        f16x4 qr = *(const f16x4*)(Q + offr);
        f16x4 qi = *(const f16x4*)(Q + offr + 2048);
        #pragma unroll
        for (int r = 0; r < 4; ++r) {
          float m1 = ac1[fr][fc][r], m2 = ac2[fr][fc][r], m3 = ac3[fr][fc][r];
          vr[r] = (f16)(2.0f * (m1 - m2) - (float)qr[r]);
          vi[r] = (f16)(2.0f * (m3 - m1 - m2) - (float)qi[r]);
        }
      } else {
        #pragma unroll
        for (int r = 0; r < 4; ++r) {
          float m1 = ac1[fr][fc][r], m2 = ac2[fr][fc][r], m3 = ac3[fr][fc][r];
          vr[r] = (f16)(m1 - m2);
          vi[r] = (f16)(m3 - m1 - m2);
        }
      }
      *(f16x4*)(Q + offr) = vr;
      *(f16x4*)(Q + offr + 2048) = vi;
    }
  }
}

// ---------------------------------------------------------------------------
// contract_k2 (r18, unchanged): K-PAIRED, t-block 2, remapped inner loop,
// early out-RMW read. Grid (32,32,4); kbase==0 initializes with bias.
// ---------------------------------------------------------------------------
template <bool CPLX>
__global__ __launch_bounds__(256, 3) void contract_k2(
    const f16* __restrict__ Pa, const f16* __restrict__ Pb,
    const uint2* __restrict__ wpk,
    const float* __restrict__ biasr, const float* __restrict__ biasi,
    float* __restrict__ out, int kbase) {
  __shared__ __align__(16) uint32_t Plds[128 * 64];          // 32KB (pr,pi) half2
  __shared__ __align__(16) uint32_t WA[96 * 32];             // 12KB (wr,-wi)
  __shared__ __align__(16) uint32_t WB[CPLX ? 96 * 32 : 32]; // 12KB (wi, wr)

  const int t = threadIdx.x;
  const int n0 = blockIdx.x * 64;
  const int t0 = blockIdx.y * 2;
  const int b = blockIdx.z;
  const int og = t & 7;          // o = og*4 .. og*4+3
  const int ng = (t >> 3) & 15;  // n = n0 + ng*4 .. +3
  const int tsl = t >> 7;        // t = t0 + tsl

  float4 cur[4];
  if (!CPLX) {
    if (kbase == 0) {
      float4 bv = *(const float4*)(biasr + og * 4);
      #pragma unroll
      for (int nn = 0; nn < 4; ++nn) cur[nn] = bv;
    } else {
      const int tt = t0 + tsl;
      #pragma unroll
      for (int nn = 0; nn < 4; ++nn) {
        size_t n = (size_t)n0 + ng * 4 + nn;
        size_t ob = (((size_t)b * Nn + n) * Tn + tt) * COn + og * 4;
        cur[nn] = *(const float4*)(out + ob);
      }
    }
  }

  float aR[4][4] = {};
  float aI[4][4] = {};

  for (int h = 0; h < 2; ++h) {
    if (h) __syncthreads();
    const f16* Pc = h ? Pb : Pa;
    const int k = kbase + h;

    #pragma unroll
    for (int it = 0; it < 4; ++it) {
      int task = it * 256 + t;
      int row = task >> 3, oc = task & 7;
      int tp = (t0 - 2) * 32 + row;
      uint4 ur = {0, 0, 0, 0}, ui = {0, 0, 0, 0};
      if (tp >= 0) {
        size_t goff = ((size_t)b * 2048 + tp) * 4096 + n0 + oc * 8;
        ur = *(const uint4*)(Pc + goff);
        ui = *(const uint4*)(Pc + goff + 2048);
      }
      uint32_t* dst = &Plds[row * 64 + oc * 8];
      dst[0] = (ur.x & 0xffffu) | (ui.x << 16);
      dst[1] = (ur.x >> 16) | (ui.x & 0xffff0000u);
      dst[2] = (ur.y & 0xffffu) | (ui.y << 16);
      dst[3] = (ur.y >> 16) | (ui.y & 0xffff0000u);
      dst[4] = (ur.z & 0xffffu) | (ui.z << 16);
      dst[5] = (ur.z >> 16) | (ui.z & 0xffff0000u);
      dst[6] = (ur.w & 0xffffu) | (ui.w << 16);
      dst[7] = (ur.w >> 16) | (ui.w & 0xffff0000u);
    }
    #pragma unroll
    for (int it = 0; it < 12; ++it) {
      int idx = it * 256 + t;
      int q = idx >> 5, o = idx & 31;
      int tau = 2 - (q >> 5), ci = q & 31;
      uint2 wv = wpk[((k * TAUn + tau) * CIn + ci) * COn + o];
      WA[idx] = wv.x;
      if (CPLX) WB[idx] = wv.y;
    }
    __syncthreads();

    #pragma unroll 4
    for (int q = 0; q < 96; ++q) {
      uint4 wa = *(const uint4*)&WA[q * 32 + og * 4];
      const uint32_t* wap = &wa.x;
      uint4 wb;
      const uint32_t* wbp = &wb.x;
      if (CPLX) wb = *(const uint4*)&WB[q * 32 + og * 4];
      int row = tsl * 32 + q;
      uint4 pp = *(const uint4*)&Plds[row * 64 + ng * 4];
      const uint32_t* ppp = &pp.x;
      #pragma unroll
      for (int nn = 0; nn < 4; ++nn) {
        f16x2 hv = __builtin_bit_cast(f16x2, ppp[nn]);
        #pragma unroll
        for (int oo = 0; oo < 4; ++oo)
          aR[nn][oo] = fdot2(hv, __builtin_bit_cast(f16x2, wap[oo]), aR[nn][oo]);
        if (CPLX) {
          #pragma unroll
          for (int oo = 0; oo < 4; ++oo)
            aI[nn][oo] = fdot2(hv, __builtin_bit_cast(f16x2, wbp[oo]), aI[nn][oo]);
        }
      }
    }
  }

  const int tt = t0 + tsl;
  #pragma unroll
  for (int nn = 0; nn < 4; ++nn) {
    size_t n = (size_t)n0 + ng * 4 + nn;
    size_t ob = (((size_t)b * Nn + n) * Tn + tt) * COn + og * 4;
    if (!CPLX) {
      float4 v;
      v.x = aR[nn][0] + cur[nn].x;
      v.y = aR[nn][1] + cur[nn].y;
      v.z = aR[nn][2] + cur[nn].z;
      v.w = aR[nn][3] + cur[nn].w;
      *(float4*)(out + ob) = v;
    } else {
      float* po = out + ob * 2;
      float4 lo, hi;
      lo.x = aR[nn][0]; lo.y = aI[nn][0];
      lo.z = aR[nn][1]; lo.w = aI[nn][1];
      hi.x = aR[nn][2]; hi.y = aI[nn][2];
      hi.z = aR[nn][3]; hi.w = aI[nn][3];
      float4 c0, c1;
      if (kbase == 0) {
        const float* pr = biasr + og * 4;
        const float* pi = biasi + og * 4;
        c0 = make_float4(pr[0], pi[0], pr[1], pi[1]);
        c1 = make_float4(pr[2], pi[2], pr[3], pi[3]);
      } else {
        c0 = *(const float4*)(po);
        c1 = *(const float4*)(po + 4);
      }
      lo.x += c0.x; lo.y += c0.y; lo.z += c0.z; lo.w += c0.w;
      hi.x += c1.x; hi.y += c1.y; hi.z += c1.z; hi.w += c1.w;
      *(float4*)(po) = lo;
      *(float4*)(po + 4) = hi;
    }
  }
}

// ---------------------------------------------------------------------------
extern "C" void kernel_launch(void* const* d_in, const int* in_sizes, int n_in,
                              void* d_out, int out_size, void* d_ws, size_t ws_size,
                              hipStream_t stream) {
  (void)in_sizes; (void)n_in;
  const float* xr = (const float*)d_in[0];
  const float* xi = (const float*)d_in[1];
  const float* gr = (const float*)d_in[2];
  const float* gi = (const float*)d_in[3];
  const float* wr = (const float*)d_in[4];
  const float* wi = (const float*)d_in[5];
  const float* biasr = (const float*)d_in[6];
  const float* biasi = (const float*)d_in[7];
  float* out = (float*)d_out;

  const size_t PPLANE = (size_t)Jn * 4096 * sizeof(f16);  // 67,108,864 (combined)
  const size_t GPLANE = (size_t)Nn * Nn * sizeof(f16);    // 8,388,608
  const size_t WPK = (size_t)Kn * TAUn * CIn * COn * 8;   // 147,456
  if (ws_size < 2 * PPLANE + 2 * GPLANE + WPK) return;

  char* ws = (char*)d_ws;
  f16* P0 = (f16*)(ws);
  f16* P1 = (f16*)(ws + PPLANE);
  f16* Gr = (f16*)(ws + 2 * PPLANE);
  f16* Gi = (f16*)(ws + 2 * PPLANE + GPLANE);
  uint2* wpk = (uint2*)(ws + 2 * PPLANE + 2 * GPLANE);

  const bool cplx = (out_size == 2 * Bn * Nn * Tn * COn);

  pack_gso<<<dim3(4096), dim3(256), 0, stream>>>(gr, gi, Gr, Gi);
  pack_x<<<dim3(32, 32, 4), dim3(256), 0, stream>>>(xr, xi, P0);
  pack_w<<<dim3(72), dim3(256), 0, stream>>>(wr, wi, wpk);

  #define CONTRACT2(KB, Pa, Pb)                                                    \
    do {                                                                           \
      if (cplx)                                                                    \
        contract_k2<true><<<dim3(32, 32, 4), dim3(256), 0, stream>>>(              \
            Pa, Pb, wpk, biasr, biasi, out, KB);                                   \
      else                                                                         \
        contract_k2<false><<<dim3(32, 32, 4), dim3(256), 0, stream>>>(             \
            Pa, Pb, wpk, biasr, biasi, out, KB);                                   \
    } while (0)

  // Sequence (hazard-checked): every in-place gemm write lands after the
  // pair-contract that read that slot (stream-serialized).
  cheb_gemm3<0><<<dim3(2048), dim3(256), 49152, stream>>>(Gr, Gi, P0, P1);  // P1
  CONTRACT2(0, P0, P1);                                                     // k=0,1
  cheb_gemm3<1><<<dim3(2048), dim3(256), 49152, stream>>>(Gr, Gi, P1, P0);  // P2 over P0
  cheb_gemm3<1><<<dim3(2048), dim3(256), 49152, stream>>>(Gr, Gi, P0, P1);  // P3 over P1
  CONTRACT2(2, P0, P1);                                                     // k=2,3
  cheb_gemm3<1><<<dim3(2048), dim3(256), 49152, stream>>>(Gr, Gi, P1, P0);  // P4 over P2
  cheb_gemm3<1><<<dim3(2048), dim3(256), 49152, stream>>>(Gr, Gi, P0, P1);  // P5 over P3
  CONTRACT2(4, P0, P1);                                                     // k=4,5
  #undef CONTRACT2
}

// Round 21
// 1799.560 us; speedup vs baseline: 1.0585x; 1.0585x over previous
//
#include <hip/hip_runtime.h>
#include <stdint.h>

// Problem constants (ComplexChebTemporalConv)
#define Bn 4
#define Nn 2048
#define Tn 64
#define CIn 32
#define COn 32
#define Kn 6
#define TAUn 3
#define Jn 8192  // B*T*CI

typedef _Float16 f16;
typedef _Float16 f16x2 __attribute__((ext_vector_type(2)));
typedef _Float16 f16x4 __attribute__((ext_vector_type(4)));
typedef _Float16 f16x8 __attribute__((ext_vector_type(8)));
typedef float f32x4 __attribute__((ext_vector_type(4)));

#if defined(__has_builtin)
#if __has_builtin(__builtin_amdgcn_fdot2)
#define HAVE_FDOT2 1
#endif
#endif

__device__ __forceinline__ float fdot2(f16x2 a, f16x2 b, float c) {
#ifdef HAVE_FDOT2
  return __builtin_amdgcn_fdot2(a, b, c, false);
#else
  return c + (float)a[0] * (float)b[0] + (float)a[1] * (float)b[1];
#endif
}

__device__ __forceinline__ void gld_lds16(const void* g, void* l) {
  auto gp = (const __attribute__((address_space(1))) uint32_t*)(uintptr_t)g;
  auto lp = (__attribute__((address_space(3))) uint32_t*)(uint32_t)(uintptr_t)l;
  __builtin_amdgcn_global_load_lds(gp, lp, 16, 0, 0);
}

// ---------------------------------------------------------------------------
// pack_gso: fp32 gso planes -> f16 planes (row-major [n][m])
// ---------------------------------------------------------------------------
__global__ __launch_bounds__(256) void pack_gso(const float* __restrict__ gr,
                                                const float* __restrict__ gi,
                                                f16* __restrict__ Gr,
                                                f16* __restrict__ Gi) {
  int u = blockIdx.x * 256 + threadIdx.x;
  float4 vr = ((const float4*)gr)[u];
  float4 vi = ((const float4*)gi)[u];
  f16x4 hr, hi;
  hr[0] = (f16)vr.x; hr[1] = (f16)vr.y; hr[2] = (f16)vr.z; hr[3] = (f16)vr.w;
  hi[0] = (f16)vi.x; hi[1] = (f16)vi.y; hi[2] = (f16)vi.z; hi[3] = (f16)vi.w;
  ((f16x4*)Gr)[u] = hr;
  ((f16x4*)Gi)[u] = hi;
}

// ---------------------------------------------------------------------------
// pack_x: x [b][n][q] fp32 -> combined P0[j=b*2048+q][4096]: re at col n, im at 2048+n
// ---------------------------------------------------------------------------
__global__ __launch_bounds__(256) void pack_x(const float* __restrict__ xr,
                                              const float* __restrict__ xi,
                                              f16* __restrict__ P0) {
  __shared__ float tile[64][65];
  const int t = threadIdx.x;
  const int q0 = blockIdx.x * 64;
  const int n0 = blockIdx.y * 64;
  const int b = blockIdx.z;
  const int rr = t >> 4;
  const int cc = (t & 15) * 4;
  #pragma unroll
  for (int plane = 0; plane < 2; ++plane) {
    const float* src = plane ? xi : xr;
    if (plane) __syncthreads();
    #pragma unroll
    for (int it = 0; it < 4; ++it) {
      int n = it * 16 + rr;
      float4 v = *(const float4*)(src + ((size_t)b * Nn + n0 + n) * 2048 + q0 + cc);
      tile[n][cc + 0] = v.x; tile[n][cc + 1] = v.y;
      tile[n][cc + 2] = v.z; tile[n][cc + 3] = v.w;
    }
    __syncthreads();
    #pragma unroll
    for (int it = 0; it < 4; ++it) {
      int q = it * 16 + rr;
      f16x4 hv;
      hv[0] = (f16)tile[cc + 0][q];
      hv[1] = (f16)tile[cc + 1][q];
      hv[2] = (f16)tile[cc + 2][q];
      hv[3] = (f16)tile[cc + 3][q];
      *(f16x4*)(P0 + ((size_t)b * 2048 + q0 + q) * 4096 + plane * 2048 + n0 + cc) = hv;
    }
  }
}

// ---------------------------------------------------------------------------
// pack_w: wpk[idx].x = (wr, -wi), wpk[idx].y = (wi, wr); idx = [k][tau][ci][co]
// ---------------------------------------------------------------------------
__global__ __launch_bounds__(256) void pack_w(const float* __restrict__ wr,
                                              const float* __restrict__ wi,
                                              uint2* __restrict__ wpk) {
  int idx = blockIdx.x * 256 + threadIdx.x;
  if (idx >= Kn * TAUn * CIn * COn) return;
  float r = wr[idx], i = wi[idx];
  uint16_t hr = __builtin_bit_cast(uint16_t, (f16)r);
  uint16_t hi = __builtin_bit_cast(uint16_t, (f16)i);
  uint16_t hni = __builtin_bit_cast(uint16_t, (f16)(-i));
  uint2 o;
  o.x = (uint32_t)hr | ((uint32_t)hni << 16);
  o.y = (uint32_t)hi | ((uint32_t)hr << 16);
  wpk[idx] = o;
}

// ---------------------------------------------------------------------------
// cheb_gemm3 r21: Karatsuba GEMM (r19, reverted to 2 blocks/CU) with
// TRIPLE-PARITY LDS rotation -> ONE barrier per K-tile (mid lgkm+bar DROPPED).
//   Parities 24KB each (Ar 8K | Ai 8K | Br 4K | Bi 4K), 3 x 24 = 72KB.
//   Tile kt reads parity kt%3; stages tile kt+2 into (kt+2)%3 == (kt-1)%3.
//   WAR proof: parity (kt-1)%3's last frag-reads were in tile kt-1; in-order
//   issue => tile-(kt-1) MFMA issue => lgkm drain of those reads => precedes
//   every wave's arrival at gate kt; gate barrier publishes => stages issued
//   after gate kt cannot race. RAW: gate vmcnt(6) retires tile kt's 6 ops
//   (queue: kt's 6 oldest + kt+1's 6 in flight; prologue = tiles 0,1 = 12).
//   m1 = Gr.Pr, m2 = Gi.Pi, m3 = (Gr+Gi).(Pr+Pi);
//   Cr = m1 - m2, Ci = m3 - m1 - m2 (sums in-register, -25% FLOPs).
// 256 thr = 4 waves (2M x 2N); tile 128(n) x 64(j), BK=32, wave 64x32.
// Per tile: gate vmcnt(6)+bar; 12 frag ds_reads; 6 stage ops (kt+2);
//   MFMA m1(8), m2(8), reg-sums, m3(8) with setprio (compiler lgkm waits).
// Staging/un-swizzle algebra r14-proven: kcg = (tid&3)^((tid>>3)&3);
//   read chunk = sub^((rr>>1)&3).
// Epilogue: Cr -> Q[j][n], Ci -> Q[j][2048+n]; MODE 1: Q = 2C - Q in place.
// XCD swizzle: xcd owns bj 16 x bn 16; window 8x8 per quadrant.
// ---------------------------------------------------------------------------
template <int MODE>
__global__ __launch_bounds__(256, 2) void cheb_gemm3(
    const f16* __restrict__ Gr, const f16* __restrict__ Gi,
    const f16* __restrict__ P, f16* __restrict__ Q) {
  extern __shared__ __align__(16) char lds[];
  f16* L = (f16*)lds;

  const int tid = threadIdx.x;
  const int lane = tid & 63;
  const int w = tid >> 6;
  const int wm = w >> 1;              // 0..1 : 64-row n-strip
  const int wn = w & 1;               // 0..1 : 32-row j-strip
  const int sub = lane >> 4, rr = lane & 15;

  const int bid = blockIdx.x;
  const int xcd = bid & 7;
  const int l = bid >> 3;             // 0..255 in-XCD
  const int s = l & 63, w2 = l >> 6;  // window pos / quadrant
  const int bj = xcd * 16 + (w2 & 1) * 8 + (s >> 3);  // 0..127
  const int bn = (w2 >> 1) * 8 + (s & 7);             // 0..15
  const int n0 = bn * 128, j0 = bj * 64;

  // ---- staging invariants (coalesced, global-side swizzle; r14 algebra) ----
  const int srow = tid >> 2;                        // 0..63
  const int kcg = (tid & 3) ^ ((tid >> 3) & 3);     // swizzled 16B k-chunk
  const size_t aoffg = (size_t)(n0 + srow) * 2048 + kcg * 8;
  const size_t boffg = (size_t)(j0 + srow) * 4096 + kcg * 8;
  const int sdst = w * 512;                         // wave-uniform LDS base

  // ---- frag-read invariants (un-swizzle) ----
  const int arb = rr * 32 + (sub ^ ((rr >> 1) & 3)) * 8;

  // parity layout (f16 elems): base = parity*12288;
  //   Ar +0 (4096), Ai +4096 (4096), Br +8192 (2048), Bi +10240 (2048)
  auto stageA = [&](const f16* plane, int kcol, int slot) {  // 128r x 32k, 2 ops
    #pragma unroll
    for (int p = 0; p < 2; ++p)
      gld_lds16(plane + aoffg + p * 131072 + kcol,
                L + slot + p * 2048 + sdst);
  };
  auto stageB = [&](int pl, int kcol, int slot) {            // 64r x 32k, 1 op
    gld_lds16(P + boffg + pl * 2048 + kcol, L + slot + sdst);
  };

  f32x4 ac1[4][2] = {}, ac2[4][2] = {}, ac3[4][2] = {};
  f16x8 ar[4], ai[4], br[2], bi[2];

  // prologue: tiles 0 (parity 0), 1 (parity 1) in queue order (12 ops)
  stageA(Gr, 0, 0);
  stageA(Gi, 0, 4096);
  stageB(0, 0, 8192);
  stageB(1, 0, 10240);
  stageA(Gr, 32, 12288);
  stageA(Gi, 32, 16384);
  stageB(0, 32, 20480);
  stageB(1, 32, 22528);

  int pbR = 0, pbN = 12288, pbS = 24576;  // read / next / stage-target bases

  for (int kt = 0; kt < 64; ++kt) {
    const int kcol2 = ((kt + 2) & 63) * 32;  // wrap -> dummy restage

    // gate: tile kt's 6 ops retired; tile kt+1's 6 stay in flight
    asm volatile("s_waitcnt vmcnt(6)" ::: "memory");
    __builtin_amdgcn_s_barrier();

    // frag reads (12 x ds_read_b128) from parity pbR
    #pragma unroll
    for (int f = 0; f < 4; ++f) {
      int ro = wm * 2048 + f * 512 + arb;
      ar[f] = *(const f16x8*)(L + pbR + ro);
      ai[f] = *(const f16x8*)(L + pbR + 4096 + ro);
    }
    #pragma unroll
    for (int fc = 0; fc < 2; ++fc) {
      int ro = wn * 1024 + fc * 512 + arb;
      br[fc] = *(const f16x8*)(L + pbR + 8192 + ro);
      bi[fc] = *(const f16x8*)(L + pbR + 10240 + ro);
    }

    // stage tile kt+2 into parity pbS (WAR covered by the gate; see header)
    stageA(Gr, kcol2, pbS);
    stageA(Gi, kcol2, pbS + 4096);
    stageB(0, kcol2, pbS + 8192);
    stageB(1, kcol2, pbS + 10240);

    __builtin_amdgcn_s_setprio(1);
    #pragma unroll
    for (int f = 0; f < 4; ++f)
      #pragma unroll
      for (int fc = 0; fc < 2; ++fc)
        ac1[f][fc] = __builtin_amdgcn_mfma_f32_16x16x32_f16(
            ar[f], br[fc], ac1[f][fc], 0, 0, 0);
    #pragma unroll
    for (int f = 0; f < 4; ++f)
      #pragma unroll
      for (int fc = 0; fc < 2; ++fc)
        ac2[f][fc] = __builtin_amdgcn_mfma_f32_16x16x32_f16(
            ai[f], bi[fc], ac2[f][fc], 0, 0, 0);
    __builtin_amdgcn_s_setprio(0);
    // register sums (Gs/Ps never materialized)
    #pragma unroll
    for (int f = 0; f < 4; ++f) ar[f] = ar[f] + ai[f];
    #pragma unroll
    for (int fc = 0; fc < 2; ++fc) br[fc] = br[fc] + bi[fc];
    __builtin_amdgcn_s_setprio(1);
    #pragma unroll
    for (int f = 0; f < 4; ++f)
      #pragma unroll
      for (int fc = 0; fc < 2; ++fc)
        ac3[f][fc] = __builtin_amdgcn_mfma_f32_16x16x32_f16(
            ar[f], br[fc], ac3[f][fc], 0, 0, 0);
    __builtin_amdgcn_s_setprio(0);

    // rotate parities
    int tmp = pbR; pbR = pbN; pbN = pbS; pbS = tmp;
  }

  asm volatile("s_waitcnt vmcnt(0)" ::: "memory");

  // Epilogue: Cr = m1-m2 -> Q[j][n]; Ci = m3-m1-m2 -> Q[j][2048+n].
  // C/D map: col=lane&15 (j), row=(lane>>4)*4+r (n).
  #pragma unroll
  for (int fc = 0; fc < 2; ++fc) {
    size_t j = (size_t)j0 + wn * 32 + fc * 16 + (lane & 15);
    #pragma unroll
    for (int fr = 0; fr < 4; ++fr) {
      int nn = n0 + wm * 64 + fr * 16 + ((lane >> 4) << 2);
      size_t offr = j * 4096 + nn;
      f16x4 vr, vi;
      if (MODE == 1) {
        f16x4 qr = *(const f16x4*)(Q + offr);
        f16x4 qi = *(const f16x4*)(Q + offr + 2048);
        #pragma unroll
        for (int r = 0; r < 4; ++r) {
          float m1 = ac1[fr][fc][r], m2 = ac2[fr][fc][r], m3 = ac3[fr][fc][r];
          vr[r] = (f16)(2.0f * (m1 - m2) - (float)qr[r]);
          vi[r] = (f16)(2.0f * (m3 - m1 - m2) - (float)qi[r]);
        }
      } else {
        #pragma unroll
        for (int r = 0; r < 4; ++r) {
          float m1 = ac1[fr][fc][r], m2 = ac2[fr][fc][r], m3 = ac3[fr][fc][r];
          vr[r] = (f16)(m1 - m2);
          vi[r] = (f16)(m3 - m1 - m2);
        }
      }
      *(f16x4*)(Q + offr) = vr;
      *(f16x4*)(Q + offr + 2048) = vi;
    }
  }
}

// ---------------------------------------------------------------------------
// contract_k2 (r18, unchanged): K-PAIRED, t-block 2, remapped inner loop,
// early out-RMW read. Grid (32,32,4); kbase==0 initializes with bias.
// ---------------------------------------------------------------------------
template <bool CPLX>
__global__ __launch_bounds__(256, 3) void contract_k2(
    const f16* __restrict__ Pa, const f16* __restrict__ Pb,
    const uint2* __restrict__ wpk,
    const float* __restrict__ biasr, const float* __restrict__ biasi,
    float* __restrict__ out, int kbase) {
  __shared__ __align__(16) uint32_t Plds[128 * 64];          // 32KB (pr,pi) half2
  __shared__ __align__(16) uint32_t WA[96 * 32];             // 12KB (wr,-wi)
  __shared__ __align__(16) uint32_t WB[CPLX ? 96 * 32 : 32]; // 12KB (wi, wr)

  const int t = threadIdx.x;
  const int n0 = blockIdx.x * 64;
  const int t0 = blockIdx.y * 2;
  const int b = blockIdx.z;
  const int og = t & 7;          // o = og*4 .. og*4+3
  const int ng = (t >> 3) & 15;  // n = n0 + ng*4 .. +3
  const int tsl = t >> 7;        // t = t0 + tsl

  float4 cur[4];
  if (!CPLX) {
    if (kbase == 0) {
      float4 bv = *(const float4*)(biasr + og * 4);
      #pragma unroll
      for (int nn = 0; nn < 4; ++nn) cur[nn] = bv;
    } else {
      const int tt = t0 + tsl;
      #pragma unroll
      for (int nn = 0; nn < 4; ++nn) {
        size_t n = (size_t)n0 + ng * 4 + nn;
        size_t ob = (((size_t)b * Nn + n) * Tn + tt) * COn + og * 4;
        cur[nn] = *(const float4*)(out + ob);
      }
    }
  }

  float aR[4][4] = {};
  float aI[4][4] = {};

  for (int h = 0; h < 2; ++h) {
    if (h) __syncthreads();
    const f16* Pc = h ? Pb : Pa;
    const int k = kbase + h;

    #pragma unroll
    for (int it = 0; it < 4; ++it) {
      int task = it * 256 + t;
      int row = task >> 3, oc = task & 7;
      int tp = (t0 - 2) * 32 + row;
      uint4 ur = {0, 0, 0, 0}, ui = {0, 0, 0, 0};
      if (tp >= 0) {
        size_t goff = ((size_t)b * 2048 + tp) * 4096 + n0 + oc * 8;
        ur = *(const uint4*)(Pc + goff);
        ui = *(const uint4*)(Pc + goff + 2048);
      }
      uint32_t* dst = &Plds[row * 64 + oc * 8];
      dst[0] = (ur.x & 0xffffu) | (ui.x << 16);
      dst[1] = (ur.x >> 16) | (ui.x & 0xffff0000u);
      dst[2] = (ur.y & 0xffffu) | (ui.y << 16);
      dst[3] = (ur.y >> 16) | (ui.y & 0xffff0000u);
      dst[4] = (ur.z & 0xffffu) | (ui.z << 16);
      dst[5] = (ur.z >> 16) | (ui.z & 0xffff0000u);
      dst[6] = (ur.w & 0xffffu) | (ui.w << 16);
      dst[7] = (ur.w >> 16) | (ui.w & 0xffff0000u);
    }
    #pragma unroll
    for (int it = 0; it < 12; ++it) {
      int idx = it * 256 + t;
      int q = idx >> 5, o = idx & 31;
      int tau = 2 - (q >> 5), ci = q & 31;
      uint2 wv = wpk[((k * TAUn + tau) * CIn + ci) * COn + o];
      WA[idx] = wv.x;
      if (CPLX) WB[idx] = wv.y;
    }
    __syncthreads();

    #pragma unroll 4
    for (int q = 0; q < 96; ++q) {
      uint4 wa = *(const uint4*)&WA[q * 32 + og * 4];
      const uint32_t* wap = &wa.x;
      uint4 wb;
      const uint32_t* wbp = &wb.x;
      if (CPLX) wb = *(const uint4*)&WB[q * 32 + og * 4];
      int row = tsl * 32 + q;
      uint4 pp = *(const uint4*)&Plds[row * 64 + ng * 4];
      const uint32_t* ppp = &pp.x;
      #pragma unroll
      for (int nn = 0; nn < 4; ++nn) {
        f16x2 hv = __builtin_bit_cast(f16x2, ppp[nn]);
        #pragma unroll
        for (int oo = 0; oo < 4; ++oo)
          aR[nn][oo] = fdot2(hv, __builtin_bit_cast(f16x2, wap[oo]), aR[nn][oo]);
        if (CPLX) {
          #pragma unroll
          for (int oo = 0; oo < 4; ++oo)
            aI[nn][oo] = fdot2(hv, __builtin_bit_cast(f16x2, wbp[oo]), aI[nn][oo]);
        }
      }
    }
  }

  const int tt = t0 + tsl;
  #pragma unroll
  for (int nn = 0; nn < 4; ++nn) {
    size_t n = (size_t)n0 + ng * 4 + nn;
    size_t ob = (((size_t)b * Nn + n) * Tn + tt) * COn + og * 4;
    if (!CPLX) {
      float4 v;
      v.x = aR[nn][0] + cur[nn].x;
      v.y = aR[nn][1] + cur[nn].y;
      v.z = aR[nn][2] + cur[nn].z;
      v.w = aR[nn][3] + cur[nn].w;
      *(float4*)(out + ob) = v;
    } else {
      float* po = out + ob * 2;
      float4 lo, hi;
      lo.x = aR[nn][0]; lo.y = aI[nn][0];
      lo.z = aR[nn][1]; lo.w = aI[nn][1];
      hi.x = aR[nn][2]; hi.y = aI[nn][2];
      hi.z = aR[nn][3]; hi.w = aI[nn][3];
      float4 c0, c1;
      if (kbase == 0) {
        const float* pr = biasr + og * 4;
        const float* pi = biasi + og * 4;
        c0 = make_float4(pr[0], pi[0], pr[1], pi[1]);
        c1 = make_float4(pr[2], pi[2], pr[3], pi[3]);
      } else {
        c0 = *(const float4*)(po);
        c1 = *(const float4*)(po + 4);
      }
      lo.x += c0.x; lo.y += c0.y; lo.z += c0.z; lo.w += c0.w;
      hi.x += c1.x; hi.y += c1.y; hi.z += c1.z; hi.w += c1.w;
      *(float4*)(po) = lo;
      *(float4*)(po + 4) = hi;
    }
  }
}

// ---------------------------------------------------------------------------
extern "C" void kernel_launch(void* const* d_in, const int* in_sizes, int n_in,
                              void* d_out, int out_size, void* d_ws, size_t ws_size,
                              hipStream_t stream) {
  (void)in_sizes; (void)n_in;
  const float* xr = (const float*)d_in[0];
  const float* xi = (const float*)d_in[1];
  const float* gr = (const float*)d_in[2];
  const float* gi = (const float*)d_in[3];
  const float* wr = (const float*)d_in[4];
  const float* wi = (const float*)d_in[5];
  const float* biasr = (const float*)d_in[6];
  const float* biasi = (const float*)d_in[7];
  float* out = (float*)d_out;

  const size_t PPLANE = (size_t)Jn * 4096 * sizeof(f16);  // 67,108,864 (combined)
  const size_t GPLANE = (size_t)Nn * Nn * sizeof(f16);    // 8,388,608
  const size_t WPK = (size_t)Kn * TAUn * CIn * COn * 8;   // 147,456
  if (ws_size < 2 * PPLANE + 2 * GPLANE + WPK) return;

  char* ws = (char*)d_ws;
  f16* P0 = (f16*)(ws);
  f16* P1 = (f16*)(ws + PPLANE);
  f16* Gr = (f16*)(ws + 2 * PPLANE);
  f16* Gi = (f16*)(ws + 2 * PPLANE + GPLANE);
  uint2* wpk = (uint2*)(ws + 2 * PPLANE + 2 * GPLANE);

  const bool cplx = (out_size == 2 * Bn * Nn * Tn * COn);

  pack_gso<<<dim3(4096), dim3(256), 0, stream>>>(gr, gi, Gr, Gi);
  pack_x<<<dim3(32, 32, 4), dim3(256), 0, stream>>>(xr, xi, P0);
  pack_w<<<dim3(72), dim3(256), 0, stream>>>(wr, wi, wpk);

  #define CONTRACT2(KB, Pa, Pb)                                                    \
    do {                                                                           \
      if (cplx)                                                                    \
        contract_k2<true><<<dim3(32, 32, 4), dim3(256), 0, stream>>>(              \
            Pa, Pb, wpk, biasr, biasi, out, KB);                                   \
      else                                                                         \
        contract_k2<false><<<dim3(32, 32, 4), dim3(256), 0, stream>>>(             \
            Pa, Pb, wpk, biasr, biasi, out, KB);                                   \
    } while (0)

  // Sequence (hazard-checked): every in-place gemm write lands after the
  // pair-contract that read that slot (stream-serialized).
  cheb_gemm3<0><<<dim3(2048), dim3(256), 73728, stream>>>(Gr, Gi, P0, P1);  // P1
  CONTRACT2(0, P0, P1);                                                     // k=0,1
  cheb_gemm3<1><<<dim3(2048), dim3(256), 73728, stream>>>(Gr, Gi, P1, P0);  // P2 over P0
  cheb_gemm3<1><<<dim3(2048), dim3(256), 73728, stream>>>(Gr, Gi, P0, P1);  // P3 over P1
  CONTRACT2(2, P0, P1);                                                     // k=2,3
  cheb_gemm3<1><<<dim3(2048), dim3(256), 73728, stream>>>(Gr, Gi, P1, P0);  // P4 over P2
  cheb_gemm3<1><<<dim3(2048), dim3(256), 73728, stream>>>(Gr, Gi, P0, P1);  // P5 over P3
  CONTRACT2(4, P0, P1);                                                     // k=4,5
  #undef CONTRACT2
}

// Round 22
// 1792.660 us; speedup vs baseline: 1.0626x; 1.0038x over previous
//
#include <hip/hip_runtime.h>
#include <stdint.h>

// Problem constants (ComplexChebTemporalConv)
#define Bn 4
#define Nn 2048
#define Tn 64
#define CIn 32
#define COn 32
#define Kn 6
#define TAUn 3
#define Jn 8192  // B*T*CI

typedef _Float16 f16;
typedef _Float16 f16x2 __attribute__((ext_vector_type(2)));
typedef _Float16 f16x4 __attribute__((ext_vector_type(4)));
typedef _Float16 f16x8 __attribute__((ext_vector_type(8)));
typedef float f32x4 __attribute__((ext_vector_type(4)));

template <int N> struct ic { static constexpr int v = N; };

#if defined(__has_builtin)
#if __has_builtin(__builtin_amdgcn_fdot2)
#define HAVE_FDOT2 1
#endif
#endif

__device__ __forceinline__ float fdot2(f16x2 a, f16x2 b, float c) {
#ifdef HAVE_FDOT2
  return __builtin_amdgcn_fdot2(a, b, c, false);
#else
  return c + (float)a[0] * (float)b[0] + (float)a[1] * (float)b[1];
#endif
}

__device__ __forceinline__ void gld_lds16(const void* g, void* l) {
  auto gp = (const __attribute__((address_space(1))) uint32_t*)(uintptr_t)g;
  auto lp = (__attribute__((address_space(3))) uint32_t*)(uint32_t)(uintptr_t)l;
  __builtin_amdgcn_global_load_lds(gp, lp, 16, 0, 0);
}

// ---------------------------------------------------------------------------
// pack_gso: fp32 gso planes -> f16 planes (row-major [n][m])
// ---------------------------------------------------------------------------
__global__ __launch_bounds__(256) void pack_gso(const float* __restrict__ gr,
                                                const float* __restrict__ gi,
                                                f16* __restrict__ Gr,
                                                f16* __restrict__ Gi) {
  int u = blockIdx.x * 256 + threadIdx.x;
  float4 vr = ((const float4*)gr)[u];
  float4 vi = ((const float4*)gi)[u];
  f16x4 hr, hi;
  hr[0] = (f16)vr.x; hr[1] = (f16)vr.y; hr[2] = (f16)vr.z; hr[3] = (f16)vr.w;
  hi[0] = (f16)vi.x; hi[1] = (f16)vi.y; hi[2] = (f16)vi.z; hi[3] = (f16)vi.w;
  ((f16x4*)Gr)[u] = hr;
  ((f16x4*)Gi)[u] = hi;
}

// ---------------------------------------------------------------------------
// pack_x: x [b][n][q] fp32 -> combined P0[j=b*2048+q][4096]: re at col n, im at 2048+n
// ---------------------------------------------------------------------------
__global__ __launch_bounds__(256) void pack_x(const float* __restrict__ xr,
                                              const float* __restrict__ xi,
                                              f16* __restrict__ P0) {
  __shared__ float tile[64][65];
  const int t = threadIdx.x;
  const int q0 = blockIdx.x * 64;
  const int n0 = blockIdx.y * 64;
  const int b = blockIdx.z;
  const int rr = t >> 4;
  const int cc = (t & 15) * 4;
  #pragma unroll
  for (int plane = 0; plane < 2; ++plane) {
    const float* src = plane ? xi : xr;
    if (plane) __syncthreads();
    #pragma unroll
    for (int it = 0; it < 4; ++it) {
      int n = it * 16 + rr;
      float4 v = *(const float4*)(src + ((size_t)b * Nn + n0 + n) * 2048 + q0 + cc);
      tile[n][cc + 0] = v.x; tile[n][cc + 1] = v.y;
      tile[n][cc + 2] = v.z; tile[n][cc + 3] = v.w;
    }
    __syncthreads();
    #pragma unroll
    for (int it = 0; it < 4; ++it) {
      int q = it * 16 + rr;
      f16x4 hv;
      hv[0] = (f16)tile[cc + 0][q];
      hv[1] = (f16)tile[cc + 1][q];
      hv[2] = (f16)tile[cc + 2][q];
      hv[3] = (f16)tile[cc + 3][q];
      *(f16x4*)(P0 + ((size_t)b * 2048 + q0 + q) * 4096 + plane * 2048 + n0 + cc) = hv;
    }
  }
}

// ---------------------------------------------------------------------------
// pack_w: wpk[idx].x = (wr, -wi), wpk[idx].y = (wi, wr); idx = [k][tau][ci][co]
// ---------------------------------------------------------------------------
__global__ __launch_bounds__(256) void pack_w(const float* __restrict__ wr,
                                              const float* __restrict__ wi,
                                              uint2* __restrict__ wpk) {
  int idx = blockIdx.x * 256 + threadIdx.x;
  if (idx >= Kn * TAUn * CIn * COn) return;
  float r = wr[idx], i = wi[idx];
  uint16_t hr = __builtin_bit_cast(uint16_t, (f16)r);
  uint16_t hi = __builtin_bit_cast(uint16_t, (f16)i);
  uint16_t hni = __builtin_bit_cast(uint16_t, (f16)(-i));
  uint2 o;
  o.x = (uint32_t)hr | ((uint32_t)hni << 16);
  o.y = (uint32_t)hi | ((uint32_t)hr << 16);
  wpk[idx] = o;
}

// ---------------------------------------------------------------------------
// cheb_gemm3 r22: Karatsuba GEMM, triple-parity 1-barrier schedule (r21),
// with COMPILE-TIME parity bases: K-loop unrolled x3 (63 tiles = 21x3 with
// literal parities 0,1,2 + tail tile 63 at parity 0). Read base PAR*12288
// and stage base ((PAR+2)%3)*12288 are literals -> immediate-offset ds_reads
// and gld_lds dests (r8 precedent: literal slots cut VALUBusy 23->19%).
//   Parity math: tile kt reads kt%3 (63==0 OK); stage target (kt+2)%3;
//   vmcnt(6)/WAR/queue logic identical to r21 (proven, absmax 0.0625).
//   m1 = Gr.Pr, m2 = Gi.Pi, m3 = (Gr+Gi).(Pr+Pi);
//   Cr = m1 - m2, Ci = m3 - m1 - m2 (sums in-register, -25% FLOPs).
// 256 thr = 4 waves (2M x 2N); tile 128(n) x 64(j), BK=32, wave 64x32.
// Per tile: gate vmcnt(6)+bar; 12 frag ds_reads; 6 stage ops (kt+2);
//   MFMA m1(8), m2(8), reg-sums, m3(8) with setprio.
// Staging/un-swizzle algebra r14-proven: kcg = (tid&3)^((tid>>3)&3);
//   read chunk = sub^((rr>>1)&3).
// Epilogue: Cr -> Q[j][n], Ci -> Q[j][2048+n]; MODE 1: Q = 2C - Q in place.
// XCD swizzle: xcd owns bj 16 x bn 16; window 8x8 per quadrant.
// ---------------------------------------------------------------------------
template <int MODE>
__global__ __launch_bounds__(256, 2) void cheb_gemm3(
    const f16* __restrict__ Gr, const f16* __restrict__ Gi,
    const f16* __restrict__ P, f16* __restrict__ Q) {
  extern __shared__ __align__(16) char lds[];
  f16* L = (f16*)lds;

  const int tid = threadIdx.x;
  const int lane = tid & 63;
  const int w = tid >> 6;
  const int wm = w >> 1;              // 0..1 : 64-row n-strip
  const int wn = w & 1;               // 0..1 : 32-row j-strip
  const int sub = lane >> 4, rr = lane & 15;

  const int bid = blockIdx.x;
  const int xcd = bid & 7;
  const int l = bid >> 3;             // 0..255 in-XCD
  const int s = l & 63, w2 = l >> 6;  // window pos / quadrant
  const int bj = xcd * 16 + (w2 & 1) * 8 + (s >> 3);  // 0..127
  const int bn = (w2 >> 1) * 8 + (s & 7);             // 0..15
  const int n0 = bn * 128, j0 = bj * 64;

  // ---- staging invariants (coalesced, global-side swizzle; r14 algebra) ----
  const int srow = tid >> 2;                        // 0..63
  const int kcg = (tid & 3) ^ ((tid >> 3) & 3);     // swizzled 16B k-chunk
  const size_t aoffg = (size_t)(n0 + srow) * 2048 + kcg * 8;
  const size_t boffg = (size_t)(j0 + srow) * 4096 + kcg * 8;
  const int sdst = w * 512;                         // wave-uniform LDS base

  // ---- frag-read invariants (un-swizzle) ----
  const int arb = rr * 32 + (sub ^ ((rr >> 1) & 3)) * 8;

  // parity layout (f16 elems): base = parity*12288;
  //   Ar +0 (4096), Ai +4096 (4096), Br +8192 (2048), Bi +10240 (2048)
  auto stageA = [&](const f16* plane, int kcol, int slot) {  // 128r x 32k, 2 ops
    #pragma unroll
    for (int p = 0; p < 2; ++p)
      gld_lds16(plane + aoffg + p * 131072 + kcol,
                L + slot + p * 2048 + sdst);
  };
  auto stageB = [&](int pl, int kcol, int slot) {            // 64r x 32k, 1 op
    gld_lds16(P + boffg + pl * 2048 + kcol, L + slot + sdst);
  };

  f32x4 ac1[4][2] = {}, ac2[4][2] = {}, ac3[4][2] = {};
  f16x8 ar[4], ai[4], br[2], bi[2];

  // prologue: tiles 0 (parity 0), 1 (parity 1) in queue order (12 ops)
  stageA(Gr, 0, 0);
  stageA(Gi, 0, 4096);
  stageB(0, 0, 8192);
  stageB(1, 0, 10240);
  stageA(Gr, 32, 12288);
  stageA(Gi, 32, 16384);
  stageB(0, 32, 20480);
  stageB(1, 32, 22528);

  // one K-tile with compile-time parity PAR (= kt % 3)
  auto tileP = [&](auto pc, int kt) {
    constexpr int PAR = decltype(pc)::v;
    constexpr int RB = PAR * 12288;              // read base (literal)
    constexpr int SB = ((PAR + 2) % 3) * 12288;  // stage base (literal)
    const int kcol2 = ((kt + 2) & 63) * 32;      // wrap -> dummy restage

    // gate: tile kt's 6 ops retired; tile kt+1's 6 stay in flight
    asm volatile("s_waitcnt vmcnt(6)" ::: "memory");
    __builtin_amdgcn_s_barrier();

    // frag reads (12 x ds_read_b128) from parity RB (immediate offsets)
    #pragma unroll
    for (int f = 0; f < 4; ++f) {
      int ro = wm * 2048 + f * 512 + arb;
      ar[f] = *(const f16x8*)(L + RB + ro);
      ai[f] = *(const f16x8*)(L + RB + 4096 + ro);
    }
    #pragma unroll
    for (int fc = 0; fc < 2; ++fc) {
      int ro = wn * 1024 + fc * 512 + arb;
      br[fc] = *(const f16x8*)(L + RB + 8192 + ro);
      bi[fc] = *(const f16x8*)(L + RB + 10240 + ro);
    }

    // stage tile kt+2 into parity SB (WAR covered by the gate; r21 proof)
    stageA(Gr, kcol2, SB);
    stageA(Gi, kcol2, SB + 4096);
    stageB(0, kcol2, SB + 8192);
    stageB(1, kcol2, SB + 10240);

    __builtin_amdgcn_s_setprio(1);
    #pragma unroll
    for (int f = 0; f < 4; ++f)
      #pragma unroll
      for (int fc = 0; fc < 2; ++fc)
        ac1[f][fc] = __builtin_amdgcn_mfma_f32_16x16x32_f16(
            ar[f], br[fc], ac1[f][fc], 0, 0, 0);
    #pragma unroll
    for (int f = 0; f < 4; ++f)
      #pragma unroll
      for (int fc = 0; fc < 2; ++fc)
        ac2[f][fc] = __builtin_amdgcn_mfma_f32_16x16x32_f16(
            ai[f], bi[fc], ac2[f][fc], 0, 0, 0);
    __builtin_amdgcn_s_setprio(0);
    // register sums (Gs/Ps never materialized)
    #pragma unroll
    for (int f = 0; f < 4; ++f) ar[f] = ar[f] + ai[f];
    #pragma unroll
    for (int fc = 0; fc < 2; ++fc) br[fc] = br[fc] + bi[fc];
    __builtin_amdgcn_s_setprio(1);
    #pragma unroll
    for (int f = 0; f < 4; ++f)
      #pragma unroll
      for (int fc = 0; fc < 2; ++fc)
        ac3[f][fc] = __builtin_amdgcn_mfma_f32_16x16x32_f16(
            ar[f], br[fc], ac3[f][fc], 0, 0, 0);
    __builtin_amdgcn_s_setprio(0);
  };

  // 63 tiles as 21 x {0,1,2} parities + tail tile 63 (parity 0)
  for (int k3 = 0; k3 < 21; ++k3) {
    const int ktb = k3 * 3;
    tileP(ic<0>{}, ktb);
    tileP(ic<1>{}, ktb + 1);
    tileP(ic<2>{}, ktb + 2);
  }
  tileP(ic<0>{}, 63);

  asm volatile("s_waitcnt vmcnt(0)" ::: "memory");

  // Epilogue: Cr = m1-m2 -> Q[j][n]; Ci = m3-m1-m2 -> Q[j][2048+n].
  // C/D map: col=lane&15 (j), row=(lane>>4)*4+r (n).
  #pragma unroll
  for (int fc = 0; fc < 2; ++fc) {
    size_t j = (size_t)j0 + wn * 32 + fc * 16 + (lane & 15);
    #pragma unroll
    for (int fr = 0; fr < 4; ++fr) {
      int nn = n0 + wm * 64 + fr * 16 + ((lane >> 4) << 2);
      size_t offr = j * 4096 + nn;
      f16x4 vr, vi;
      if (MODE == 1) {
        f16x4 qr = *(const f16x4*)(Q + offr);
        f16x4 qi = *(const f16x4*)(Q + offr + 2048);
        #pragma unroll
        for (int r = 0; r < 4; ++r) {
          float m1 = ac1[fr][fc][r], m2 = ac2[fr][fc][r], m3 = ac3[fr][fc][r];
          vr[r] = (f16)(2.0f * (m1 - m2) - (float)qr[r]);
          vi[r] = (f16)(2.0f * (m3 - m1 - m2) - (float)qi[r]);
        }
      } else {
        #pragma unroll
        for (int r = 0; r < 4; ++r) {
          float m1 = ac1[fr][fc][r], m2 = ac2[fr][fc][r], m3 = ac3[fr][fc][r];
          vr[r] = (f16)(m1 - m2);
          vi[r] = (f16)(m3 - m1 - m2);
        }
      }
      *(f16x4*)(Q + offr) = vr;
      *(f16x4*)(Q + offr + 2048) = vi;
    }
  }
}

// ---------------------------------------------------------------------------
// contract_k2 (r18, unchanged): K-PAIRED, t-block 2, remapped inner loop,
// early out-RMW read. Grid (32,32,4); kbase==0 initializes with bias.
// ---------------------------------------------------------------------------
template <bool CPLX>
__global__ __launch_bounds__(256, 3) void contract_k2(
    const f16* __restrict__ Pa, const f16* __restrict__ Pb,
    const uint2* __restrict__ wpk,
    const float* __restrict__ biasr, const float* __restrict__ biasi,
    float* __restrict__ out, int kbase) {
  __shared__ __align__(16) uint32_t Plds[128 * 64];          // 32KB (pr,pi) half2
  __shared__ __align__(16) uint32_t WA[96 * 32];             // 12KB (wr,-wi)
  __shared__ __align__(16) uint32_t WB[CPLX ? 96 * 32 : 32]; // 12KB (wi, wr)

  const int t = threadIdx.x;
  const int n0 = blockIdx.x * 64;
  const int t0 = blockIdx.y * 2;
  const int b = blockIdx.z;
  const int og = t & 7;          // o = og*4 .. og*4+3
  const int ng = (t >> 3) & 15;  // n = n0 + ng*4 .. +3
  const int tsl = t >> 7;        // t = t0 + tsl

  float4 cur[4];
  if (!CPLX) {
    if (kbase == 0) {
      float4 bv = *(const float4*)(biasr + og * 4);
      #pragma unroll
      for (int nn = 0; nn < 4; ++nn) cur[nn] = bv;
    } else {
      const int tt = t0 + tsl;
      #pragma unroll
      for (int nn = 0; nn < 4; ++nn) {
        size_t n = (size_t)n0 + ng * 4 + nn;
        size_t ob = (((size_t)b * Nn + n) * Tn + tt) * COn + og * 4;
        cur[nn] = *(const float4*)(out + ob);
      }
    }
  }

  float aR[4][4] = {};
  float aI[4][4] = {};

  for (int h = 0; h < 2; ++h) {
    if (h) __syncthreads();
    const f16* Pc = h ? Pb : Pa;
    const int k = kbase + h;

    #pragma unroll
    for (int it = 0; it < 4; ++it) {
      int task = it * 256 + t;
      int row = task >> 3, oc = task & 7;
      int tp = (t0 - 2) * 32 + row;
      uint4 ur = {0, 0, 0, 0}, ui = {0, 0, 0, 0};
      if (tp >= 0) {
        size_t goff = ((size_t)b * 2048 + tp) * 4096 + n0 + oc * 8;
        ur = *(const uint4*)(Pc + goff);
        ui = *(const uint4*)(Pc + goff + 2048);
      }
      uint32_t* dst = &Plds[row * 64 + oc * 8];
      dst[0] = (ur.x & 0xffffu) | (ui.x << 16);
      dst[1] = (ur.x >> 16) | (ui.x & 0xffff0000u);
      dst[2] = (ur.y & 0xffffu) | (ui.y << 16);
      dst[3] = (ur.y >> 16) | (ui.y & 0xffff0000u);
      dst[4] = (ur.z & 0xffffu) | (ui.z << 16);
      dst[5] = (ur.z >> 16) | (ui.z & 0xffff0000u);
      dst[6] = (ur.w & 0xffffu) | (ui.w << 16);
      dst[7] = (ur.w >> 16) | (ui.w & 0xffff0000u);
    }
    #pragma unroll
    for (int it = 0; it < 12; ++it) {
      int idx = it * 256 + t;
      int q = idx >> 5, o = idx & 31;
      int tau = 2 - (q >> 5), ci = q & 31;
      uint2 wv = wpk[((k * TAUn + tau) * CIn + ci) * COn + o];
      WA[idx] = wv.x;
      if (CPLX) WB[idx] = wv.y;
    }
    __syncthreads();

    #pragma unroll 4
    for (int q = 0; q < 96; ++q) {
      uint4 wa = *(const uint4*)&WA[q * 32 + og * 4];
      const uint32_t* wap = &wa.x;
      uint4 wb;
      const uint32_t* wbp = &wb.x;
      if (CPLX) wb = *(const uint4*)&WB[q * 32 + og * 4];
      int row = tsl * 32 + q;
      uint4 pp = *(const uint4*)&Plds[row * 64 + ng * 4];
      const uint32_t* ppp = &pp.x;
      #pragma unroll
      for (int nn = 0; nn < 4; ++nn) {
        f16x2 hv = __builtin_bit_cast(f16x2, ppp[nn]);
        #pragma unroll
        for (int oo = 0; oo < 4; ++oo)
          aR[nn][oo] = fdot2(hv, __builtin_bit_cast(f16x2, wap[oo]), aR[nn][oo]);
        if (CPLX) {
          #pragma unroll
          for (int oo = 0; oo < 4; ++oo)
            aI[nn][oo] = fdot2(hv, __builtin_bit_cast(f16x2, wbp[oo]), aI[nn][oo]);
        }
      }
    }
  }

  const int tt = t0 + tsl;
  #pragma unroll
  for (int nn = 0; nn < 4; ++nn) {
    size_t n = (size_t)n0 + ng * 4 + nn;
    size_t ob = (((size_t)b * Nn + n) * Tn + tt) * COn + og * 4;
    if (!CPLX) {
      float4 v;
      v.x = aR[nn][0] + cur[nn].x;
      v.y = aR[nn][1] + cur[nn].y;
      v.z = aR[nn][2] + cur[nn].z;
      v.w = aR[nn][3] + cur[nn].w;
      *(float4*)(out + ob) = v;
    } else {
      float* po = out + ob * 2;
      float4 lo, hi;
      lo.x = aR[nn][0]; lo.y = aI[nn][0];
      lo.z = aR[nn][1]; lo.w = aI[nn][1];
      hi.x = aR[nn][2]; hi.y = aI[nn][2];
      hi.z = aR[nn][3]; hi.w = aI[nn][3];
      float4 c0, c1;
      if (kbase == 0) {
        const float* pr = biasr + og * 4;
        const float* pi = biasi + og * 4;
        c0 = make_float4(pr[0], pi[0], pr[1], pi[1]);
        c1 = make_float4(pr[2], pi[2], pr[3], pi[3]);
      } else {
        c0 = *(const float4*)(po);
        c1 = *(const float4*)(po + 4);
      }
      lo.x += c0.x; lo.y += c0.y; lo.z += c0.z; lo.w += c0.w;
      hi.x += c1.x; hi.y += c1.y; hi.z += c1.z; hi.w += c1.w;
      *(float4*)(po) = lo;
      *(float4*)(po + 4) = hi;
    }
  }
}

// ---------------------------------------------------------------------------
extern "C" void kernel_launch(void* const* d_in, const int* in_sizes, int n_in,
                              void* d_out, int out_size, void* d_ws, size_t ws_size,
                              hipStream_t stream) {
  (void)in_sizes; (void)n_in;
  const float* xr = (const float*)d_in[0];
  const float* xi = (const float*)d_in[1];
  const float* gr = (const float*)d_in[2];
  const float* gi = (const float*)d_in[3];
  const float* wr = (const float*)d_in[4];
  const float* wi = (const float*)d_in[5];
  const float* biasr = (const float*)d_in[6];
  const float* biasi = (const float*)d_in[7];
  float* out = (float*)d_out;

  const size_t PPLANE = (size_t)Jn * 4096 * sizeof(f16);  // 67,108,864 (combined)
  const size_t GPLANE = (size_t)Nn * Nn * sizeof(f16);    // 8,388,608
  const size_t WPK = (size_t)Kn * TAUn * CIn * COn * 8;   // 147,456
  if (ws_size < 2 * PPLANE + 2 * GPLANE + WPK) return;

  char* ws = (char*)d_ws;
  f16* P0 = (f16*)(ws);
  f16* P1 = (f16*)(ws + PPLANE);
  f16* Gr = (f16*)(ws + 2 * PPLANE);
  f16* Gi = (f16*)(ws + 2 * PPLANE + GPLANE);
  uint2* wpk = (uint2*)(ws + 2 * PPLANE + 2 * GPLANE);

  const bool cplx = (out_size == 2 * Bn * Nn * Tn * COn);

  pack_gso<<<dim3(4096), dim3(256), 0, stream>>>(gr, gi, Gr, Gi);
  pack_x<<<dim3(32, 32, 4), dim3(256), 0, stream>>>(xr, xi, P0);
  pack_w<<<dim3(72), dim3(256), 0, stream>>>(wr, wi, wpk);

  #define CONTRACT2(KB, Pa, Pb)                                                    \
    do {                                                                           \
      if (cplx)                                                                    \
        contract_k2<true><<<dim3(32, 32, 4), dim3(256), 0, stream>>>(              \
            Pa, Pb, wpk, biasr, biasi, out, KB);                                   \
      else                                                                         \
        contract_k2<false><<<dim3(32, 32, 4), dim3(256), 0, stream>>>(             \
            Pa, Pb, wpk, biasr, biasi, out, KB);                                   \
    } while (0)

  // Sequence (hazard-checked): every in-place gemm write lands after the
  // pair-contract that read that slot (stream-serialized).
  cheb_gemm3<0><<<dim3(2048), dim3(256), 73728, stream>>>(Gr, Gi, P0, P1);  // P1
  CONTRACT2(0, P0, P1);                                                     // k=0,1
  cheb_gemm3<1><<<dim3(2048), dim3(256), 73728, stream>>>(Gr, Gi, P1, P0);  // P2 over P0
  cheb_gemm3<1><<<dim3(2048), dim3(256), 73728, stream>>>(Gr, Gi, P0, P1);  // P3 over P1
  CONTRACT2(2, P0, P1);                                                     // k=2,3
  cheb_gemm3<1><<<dim3(2048), dim3(256), 73728, stream>>>(Gr, Gi, P1, P0);  // P4 over P2
  cheb_gemm3<1><<<dim3(2048), dim3(256), 73728, stream>>>(Gr, Gi, P0, P1);  // P5 over P3
  CONTRACT2(4, P0, P1);                                                     // k=4,5
  #undef CONTRACT2
}